// Round 2
// baseline (417.611 us; speedup 1.0000x reference)
//
#include <hip/hip_runtime.h>
#include <cstdint>
#include <cstddef>

// Problem constants (fixed by the reference)
#define TOKENS 8192
#define INF    4096
#define OUTF   4096

typedef int v4i __attribute__((ext_vector_type(4)));

// ---------------------------------------------------------------------------
// Kernel 1: pack int32 -> int8 into workspace (x8 then w8, row-major).
// x: 8192x4096 ints -> 32MB i8 ; w: 4096x4096 ints -> 16MB i8. ws needs 48MB.
// ---------------------------------------------------------------------------
__global__ __launch_bounds__(256) void pack_i8_kernel(
    const int* __restrict__ xi, const int* __restrict__ wi,
    uint8_t* __restrict__ x8, uint8_t* __restrict__ w8) {
  const int NX = (TOKENS * INF) / 4;   // 8388608 chunks of 4 ints (x)
  const int NT = 2048 * 256;           // total threads = 524288
  int tid = blockIdx.x * 256 + threadIdx.x;
#pragma unroll 1
  for (int it = 0; it < 24; ++it) {    // 24 * 524288 = 12582912 = all chunks
    int c = it * NT + tid;
    const int4* src;
    unsigned* dst;
    if (c < NX) {
      src = (const int4*)xi + c;
      dst = (unsigned*)x8 + c;
    } else {
      int c2 = c - NX;
      src = (const int4*)wi + c2;
      dst = (unsigned*)w8 + c2;
    }
    int4 v = *src;
    *dst = (v.x & 255) | ((v.y & 255) << 8) | ((v.z & 255) << 16) |
           (((unsigned)v.w) << 24);
  }
}

// ---------------------------------------------------------------------------
// Branchless exact-GeLU via Abramowitz-Stegun 7.1.26 erf (|err| <= 1.5e-7).
// ---------------------------------------------------------------------------
__device__ __forceinline__ float gelu_exact(float y) {
  float x = y * 0.70710678118654752f;   // y / sqrt(2)
  float s = fabsf(x);
  float t = __builtin_amdgcn_rcpf(fmaf(s, 0.3275911f, 1.0f));
  float p = t * fmaf(t, fmaf(t, fmaf(t, fmaf(t, 1.061405429f, -1.453152027f),
                                     1.421413741f), -0.284496736f),
                     0.254829592f);
  float e = __expf(-s * s);
  float er = fmaf(-p, e, 1.0f);         // erf(|x|)
  er = copysignf(er, x);
  return 0.5f * y * (1.0f + er);
}

// ---------------------------------------------------------------------------
// Kernel 2: int8 GEMM, BM=BN=256, BK=128, 512 threads (8 waves, 2x4 grid),
// wave tile 128x64 via 8x4 frags of mfma_i32_16x16x64_i8.
// LDS: single 64KB buffer, [256][128] i8 per operand, XOR slot swizzle
// (chunk (r,s) stored at slot s^(r&7); 8 slots of 16B per 128B row) ->
// conflict-free ds_read_b128 / ds_write_b128.
// Pipeline: 2-phase; next tile's global->reg loads issued under compute.
// Output: int32 elements (harness reads integer outputs via np.int32).
// ---------------------------------------------------------------------------
__global__ __launch_bounds__(512, 2) void gemm_i8_gelu_q_kernel(
    const uint8_t* __restrict__ x8, const uint8_t* __restrict__ w8,
    const float* __restrict__ bias, const float* __restrict__ pa,
    const float* __restrict__ pb, int* __restrict__ out) {
  __shared__ char sm[65536];           // A at 0 (32KB), B at 32768 (32KB)

  const int tid = threadIdx.x;
  const int l   = tid & 63;
  const int wv  = tid >> 6;
  const int wr  = wv >> 2;             // 0..1  (M wave row)
  const int wc  = wv & 3;              // 0..3  (N wave col)
  const int lr  = l & 15;              // fragment row
  const int lg  = l >> 4;              // k-group 0..3

  // XCD-aware bijective swizzle (512 blocks % 8 == 0): each XCD gets 4
  // contiguous A row-bands x full N sweep -> A band L2-resident.
  int id = blockIdx.x;
  int wg = (id & 7) * 64 + (id >> 3);
  const int m0 = (wg >> 4) * 256;      // 32 row-bands
  const int n0 = (wg & 15) * 256;      // 16 col-bands

  const float av = pa[0];
  const float bv = pb[0];

  // ---- staging addressing (per-lane, loop-invariant) ----
  // 16B chunk c = i*512 + tid ; r = i*64 + (tid>>3) ; slot = tid&7.
  const int srow  = tid >> 3;                          // 0..63
  const int sslot = tid & 7;
  const int wslot = ((sslot ^ (srow & 7)) << 4);       // swizzled byte slot
  const uint8_t* ga = x8 + (size_t)(m0 + srow) * INF + sslot * 16;
  const uint8_t* gb = w8 + (size_t)(n0 + srow) * INF + sslot * 16;
  const int lds_w = srow * 128 + wslot;                // + i*8192 (+32768 B)

  // ---- fragment read offsets ----
  int aoff[8], boff[4], sb[2];
#pragma unroll
  for (int m = 0; m < 8; ++m) aoff[m] = (wr * 128 + m * 16 + lr) * 128;
#pragma unroll
  for (int n = 0; n < 4; ++n) boff[n] = 32768 + (wc * 64 + n * 16 + lr) * 128;
#pragma unroll
  for (int s = 0; s < 2; ++s) sb[s] = (((s * 4 + lg) ^ (l & 7)) << 4);

  v4i acc[8][4];
#pragma unroll
  for (int m = 0; m < 8; ++m)
#pragma unroll
    for (int n = 0; n < 4; ++n) acc[m][n] = (v4i){0, 0, 0, 0};

  v4i avr[4], bvr[4];
#pragma unroll
  for (int i = 0; i < 4; ++i) {        // prologue: tile 0 -> regs
    avr[i] = *(const v4i*)(ga + (size_t)i * 64 * INF);
    bvr[i] = *(const v4i*)(gb + (size_t)i * 64 * INF);
  }

  const int NKT = INF / 128;           // 32 K-tiles
#pragma unroll 1
  for (int kt = 0; kt < NKT; ++kt) {
    // barrier A: all waves finished ds_reads of previous tile
    asm volatile("" ::: "memory");
    __builtin_amdgcn_s_barrier();
    asm volatile("" ::: "memory");
#pragma unroll
    for (int i = 0; i < 4; ++i) {      // regs -> LDS (swizzled slots)
      *(v4i*)(sm + i * 8192 + lds_w)         = avr[i];
      *(v4i*)(sm + 32768 + i * 8192 + lds_w) = bvr[i];
    }
    __syncthreads();                   // barrier B: writes visible

    if (kt + 1 < NKT) {                // prefetch next tile -> regs
      const uint8_t* ga2 = ga + (size_t)(kt + 1) * 128;
      const uint8_t* gb2 = gb + (size_t)(kt + 1) * 128;
#pragma unroll
      for (int i = 0; i < 4; ++i) {
        avr[i] = *(const v4i*)(ga2 + (size_t)i * 64 * INF);
        bvr[i] = *(const v4i*)(gb2 + (size_t)i * 64 * INF);
      }
    }

#pragma unroll
    for (int s = 0; s < 2; ++s) {      // two K=64 sub-steps
      v4i Af[8], Bf[4];
#pragma unroll
      for (int m = 0; m < 8; ++m) Af[m] = *(const v4i*)(sm + aoff[m] + sb[s]);
#pragma unroll
      for (int n = 0; n < 4; ++n) Bf[n] = *(const v4i*)(sm + boff[n] + sb[s]);
#pragma unroll
      for (int m = 0; m < 8; ++m)
#pragma unroll
        for (int n = 0; n < 4; ++n)
          acc[m][n] = __builtin_amdgcn_mfma_i32_16x16x64_i8(Af[m], Bf[n],
                                                            acc[m][n], 0, 0, 0);
    }
  }

  // ---- epilogue: dequant + bias + exact GeLU + requant, write INT32 ----
  float bvals[4];
#pragma unroll
  for (int n = 0; n < 4; ++n) bvals[n] = bias[n0 + wc * 64 + n * 16 + lr];

#pragma unroll
  for (int m = 0; m < 8; ++m) {
    int rowb = m0 + wr * 128 + m * 16 + lg * 4;
#pragma unroll
    for (int q = 0; q < 4; ++q) {
      size_t rb = (size_t)(rowb + q) * OUTF;
#pragma unroll
      for (int n = 0; n < 4; ++n) {
        float f = fmaf(av, (float)acc[m][n][q], bvals[n]);
        float g = gelu_exact(f);
        float r = __builtin_rintf(g * bv);
        r = fminf(fmaxf(r, -128.0f), 127.0f);
        out[rb + (size_t)(n0 + wc * 64 + n * 16 + lr)] = (int)r;
      }
    }
  }
}

// ---------------------------------------------------------------------------
extern "C" void kernel_launch(void* const* d_in, const int* in_sizes, int n_in,
                              void* d_out, int out_size, void* d_ws,
                              size_t ws_size, hipStream_t stream) {
  const int*   xi   = (const int*)d_in[0];
  const int*   wi   = (const int*)d_in[1];
  const float* bias = (const float*)d_in[2];
  const float* pa   = (const float*)d_in[3];
  const float* pb   = (const float*)d_in[4];
  int*         out  = (int*)d_out;

  uint8_t* x8 = (uint8_t*)d_ws;                         // 33554432 B
  uint8_t* w8 = x8 + (size_t)TOKENS * INF;              // 16777216 B
  // requires ws_size >= 50331648

  pack_i8_kernel<<<2048, 256, 0, stream>>>(xi, wi, x8, w8);

  dim3 grid((TOKENS / 256) * (OUTF / 256));             // 512 blocks
  gemm_i8_gelu_q_kernel<<<grid, 512, 0, stream>>>(x8, w8, bias, pa, pb, out);
}